// Round 10
// baseline (2761.432 us; speedup 1.0000x reference)
//
#include <hip/hip_runtime.h>
#include <cfloat>
#include <climits>

#define NPTS   8192
#define SCENT  2048
#define KNEIGH 32
#define BATCH  4
#define DFEAT  64
#define FPS_T  512
#define NV     8       // v2f pairs per thread (16 points)
#define NW     8       // waves per block
#define CAP    64      // fallback candidate capacity

typedef float v2f __attribute__((ext_vector_type(2)));

// DPP max step over uint (positive-f32 bit pattern preserves order).
#define DPPMAX(u, ctrl, rmask)                                                        \
    { unsigned _t = (unsigned)__builtin_amdgcn_update_dpp(0, (int)(u), (ctrl),        \
                                                          (rmask), 0xf, false);      \
      (u) = ((u) > _t) ? (u) : _t; }

// ---------------------------------------------------------------------------
// Kernel 1: FPS. f32 fast path + exact-f64 fallback (proof as R3..R9: f32
// rounding keeps relative error << 2e-6; if no second point has dist32 >=
// v1*(1-2e-6) the f32 argmax IS the f64 argmax, and the fast path commits
// ONLY in that provably-unique case; otherwise candidates >= threshold are
// re-scored exactly in f64 vs the centroid history with lexicographic
// (d, original idx) = numpy argmax tie rule).
// R10: packed-FP32 (v_pk_*) value-only update; tie/coord recovery scan only
// on the winning wave (post-merge, gated); slot1 = u32 wave max; winner
// publishes float4{x,y,z,tie} via one ds_write_b128. Two barriers/iter.
// ---------------------------------------------------------------------------
__global__ __launch_bounds__(FPS_T, 1) void fps_kernel(const float* __restrict__ xyz,
                                                       float* __restrict__ new_xyz) {
    const int b = blockIdx.x, t = threadIdx.x;
    const int lane = t & 63, w = t >> 6;
    const float* X = xyz + (size_t)b * NPTS * 3;

    __shared__ float hx[SCENT], hy[SCENT], hz[SCENT];   // centroid history (24 KB)
    __shared__ __align__(16) unsigned slot1[2][NW];
    __shared__ __align__(16) float4 pub[2];
    __shared__ int   scand[CAP];
    __shared__ float scandX[CAP], scandY[CAP], scandZ[CAP];
    __shared__ int   scnt;
    __shared__ double sdd[2][NW];
    __shared__ double sfv[NW];
    __shared__ int    sfo[NW];
    __shared__ float  sfc[3];

    v2f px2[NV], py2[NV], pz2[NV], dist2[NV];
#pragma unroll
    for (int j = 0; j < NV; ++j) {
        int pA = t + FPS_T * j, pB = t + FPS_T * (j + NV);
        px2[j] = (v2f){X[3 * pA + 0], X[3 * pB + 0]};
        py2[j] = (v2f){X[3 * pA + 1], X[3 * pB + 1]};
        pz2[j] = (v2f){X[3 * pA + 2], X[3 * pB + 2]};
        dist2[j] = (v2f){1e10f, 1e10f};
    }
    float cx = X[0], cy = X[1], cz = X[2];
    int buf = 0;
    __syncthreads();

#pragma unroll 1
    for (int s = 0; s < SCENT; ++s) {
        if (t == 0) { hx[s] = cx; hy[s] = cy; hz[s] = cz; }

        // ---- packed value-only update ----
        const v2f cxx = {cx, cx}, cyy = {cy, cy}, czz = {cz, cz};
        v2f m2 = {-1.f, -1.f};
#pragma unroll
        for (int j = 0; j < NV; ++j) {
            v2f dx = px2[j] - cxx;
            v2f dy = py2[j] - cyy;
            v2f dz = pz2[j] - czz;
            v2f d  = __builtin_elementwise_fma(dx, dx,
                     __builtin_elementwise_fma(dy, dy, dz * dz));
            v2f nd = __builtin_elementwise_min(dist2[j], d);
            dist2[j] = nd;
            m2 = __builtin_elementwise_max(m2, nd);
        }
        const float m = fmaxf(m2.x, m2.y);

        // ---- wave max via DPP (pure VALU) ----
        unsigned myU = __float_as_uint(m);
        unsigned u = myU;
        DPPMAX(u, 0x111, 0xf);   // row_shr:1
        DPPMAX(u, 0x112, 0xf);   // row_shr:2
        DPPMAX(u, 0x114, 0xf);   // row_shr:4
        DPPMAX(u, 0x118, 0xf);   // row_shr:8
        DPPMAX(u, 0x142, 0xa);   // row_bcast:15
        DPPMAX(u, 0x143, 0xc);   // row_bcast:31
        const unsigned wu = (unsigned)__builtin_amdgcn_readlane((int)u, 63);
        if (lane == 0) slot1[buf][w] = wu;
        __syncthreads();                                  // B1

        // ---- merge: 8 slot reads + umax tree (all threads, uniform) ----
        unsigned sv[NW];
        {
            const uint4* sp = (const uint4*)&slot1[buf][0];
            uint4 a = sp[0], c = sp[1];
            sv[0] = a.x; sv[1] = a.y; sv[2] = a.z; sv[3] = a.w;
            sv[4] = c.x; sv[5] = c.y; sv[6] = c.z; sv[7] = c.w;
        }
        unsigned gu = sv[0];
#pragma unroll
        for (int k = 1; k < NW; ++k) gu = (sv[k] > gu) ? sv[k] : gu;
        const float gv   = __uint_as_float(gu);
        const float gthf = __fmul_rn(gv, 0.999998f);
        const unsigned ugth = __float_as_uint(gthf);
        int nw = 0, k0 = 0;
#pragma unroll
        for (int k = NW - 1; k >= 0; --k) {
            nw += (sv[k] >= ugth) ? 1 : 0;
            k0 = (sv[k] == gu) ? k : k0;
        }

        // ---- winning wave only: tie count + coord recovery ----
        if (w == k0) {
            int cnt = 0;
            float wxc = 0.f, wyc = 0.f, wzc = 0.f;
#pragma unroll
            for (int j = 0; j < NV; ++j) {
                bool cA = dist2[j].x >= gthf, cB = dist2[j].y >= gthf;
                cnt += (cA ? 1 : 0) + (cB ? 1 : 0);
                bool eA = dist2[j].x == gv, eB = dist2[j].y == gv;
                wxc = eA ? px2[j].x : wxc; wxc = eB ? px2[j].y : wxc;
                wyc = eA ? py2[j].x : wyc; wyc = eB ? py2[j].y : wyc;
                wzc = eA ? pz2[j].x : wzc; wzc = eB ? pz2[j].y : wzc;
            }
            unsigned long long wb = __ballot(m == gv);
            const int wl = __ffsll(wb) - 1;
            int xi = __builtin_amdgcn_readlane((int)__float_as_uint(wxc), wl);
            int yi = __builtin_amdgcn_readlane((int)__float_as_uint(wyc), wl);
            int zi = __builtin_amdgcn_readlane((int)__float_as_uint(wzc), wl);
            unsigned long long c2 = __ballot(cnt >= 2);
            unsigned long long c1 = __ballot(cnt >= 1);
            unsigned tie = (c2 || __popcll(c1) >= 2) ? 1u : 0u;
            if (lane == 0)
                pub[buf] = make_float4(__uint_as_float(xi), __uint_as_float(yi),
                                       __uint_as_float(zi), __uint_as_float(tie));
        }
        __syncthreads();                                  // B2
        const float4 P = pub[buf];
        const unsigned tieg = __float_as_uint(P.w);

        if (nw >= 2 || tieg) {
            // ---- exact f64 fallback (block-uniform, rare) ----
            if (t == 0) scnt = 0;
            __syncthreads();
#pragma unroll
            for (int j = 0; j < NV; ++j) {
                if (dist2[j].x >= gthf) {
                    int slot = atomicAdd(&scnt, 1);
                    if (slot < CAP) {
                        scand[slot] = t + FPS_T * j;
                        scandX[slot] = px2[j].x; scandY[slot] = py2[j].x; scandZ[slot] = pz2[j].x;
                    }
                }
                if (dist2[j].y >= gthf) {
                    int slot = atomicAdd(&scnt, 1);
                    if (slot < CAP) {
                        scand[slot] = t + FPS_T * (j + NV);
                        scandX[slot] = px2[j].y; scandY[slot] = py2[j].y; scandZ[slot] = pz2[j].y;
                    }
                }
            }
            __syncthreads();
            const int mm = scnt;
            if (mm <= CAP) {
                double bd = -1.0; int bi = INT_MAX; float bx = cx, by = cy, bz = cz;
#pragma unroll 1
                for (int k = 0; k < mm; ++k) {
                    const int pos = scand[k];
                    const double pxd = (double)scandX[k], pyd = (double)scandY[k],
                                 pzd = (double)scandZ[k];
                    double dd = 1e10;
                    for (int i = t; i <= s; i += FPS_T) {
                        double ddx = __dsub_rn(pxd, (double)hx[i]);
                        double ddy = __dsub_rn(pyd, (double)hy[i]);
                        double ddz = __dsub_rn(pzd, (double)hz[i]);
                        double d = __dadd_rn(__dadd_rn(__dmul_rn(ddx, ddx), __dmul_rn(ddy, ddy)),
                                             __dmul_rn(ddz, ddz));
                        dd = fmin(dd, d);
                    }
#pragma unroll
                    for (int off = 32; off >= 1; off >>= 1)
                        dd = fmin(dd, __shfl_down(dd, off));
                    if (lane == 0) sdd[k & 1][w] = dd;
                    __syncthreads();
                    double ddm = sdd[k & 1][0];
#pragma unroll
                    for (int w2 = 1; w2 < NW; ++w2) ddm = fmin(ddm, sdd[k & 1][w2]);
                    if (ddm > bd || (ddm == bd && pos < bi)) {
                        bd = ddm; bi = pos;
                        bx = scandX[k]; by = scandY[k]; bz = scandZ[k];
                    }
                }
                cx = bx; cy = by; cz = bz;
            } else {
                // safety net: full exact scan (practically unreachable)
                double bv = -1.0; int bi = INT_MAX;
#pragma unroll 1
                for (int j = 0; j < 2 * NV; ++j) {
                    const int jj = j & (NV - 1);
                    const bool hiHalf = j >= NV;
                    const double pxd = (double)(hiHalf ? px2[jj].y : px2[jj].x);
                    const double pyd = (double)(hiHalf ? py2[jj].y : py2[jj].x);
                    const double pzd = (double)(hiHalf ? pz2[jj].y : pz2[jj].x);
                    double dd = 1e10;
                    for (int i = 0; i <= s; ++i) {
                        double ddx = __dsub_rn(pxd, (double)hx[i]);
                        double ddy = __dsub_rn(pyd, (double)hy[i]);
                        double ddz = __dsub_rn(pzd, (double)hz[i]);
                        double d = __dadd_rn(__dadd_rn(__dmul_rn(ddx, ddx), __dmul_rn(ddy, ddy)),
                                             __dmul_rn(ddz, ddz));
                        dd = fmin(dd, d);
                    }
                    int pidx = t + FPS_T * j;
                    if (dd > bv || (dd == bv && pidx < bi)) { bv = dd; bi = pidx; }
                }
#pragma unroll
                for (int off = 32; off >= 1; off >>= 1) {
                    double ov = __shfl_down(bv, off);
                    int    oi = __shfl_down(bi, off);
                    if (ov > bv || (ov == bv && oi < bi)) { bv = ov; bi = oi; }
                }
                if (lane == 0) { sfv[w] = bv; sfo[w] = bi; }
                __syncthreads();
                bv = sfv[0]; bi = sfo[0];
#pragma unroll
                for (int w2 = 1; w2 < NW; ++w2) {
                    double ov = sfv[w2]; int oi = sfo[w2];
                    if (ov > bv || (ov == bv && oi < bi)) { bv = ov; bi = oi; }
                }
                if ((bi & (FPS_T - 1)) == t) {
                    float ox = 0.f, oy = 0.f, oz = 0.f;
#pragma unroll
                    for (int j = 0; j < 2 * NV; ++j) {
                        const int jj = j & (NV - 1);
                        bool c = (bi == t + FPS_T * j);
                        bool hiHalf = j >= NV;
                        float vx = hiHalf ? px2[jj].y : px2[jj].x;
                        float vy = hiHalf ? py2[jj].y : py2[jj].x;
                        float vz = hiHalf ? pz2[jj].y : pz2[jj].x;
                        ox = c ? vx : ox; oy = c ? vy : oy; oz = c ? vz : oz;
                    }
                    sfc[0] = ox; sfc[1] = oy; sfc[2] = oz;
                }
                __syncthreads();
                cx = sfc[0]; cy = sfc[1]; cz = sfc[2];
            }
            __syncthreads();
        } else {
            cx = P.x; cy = P.y; cz = P.z;     // provably the unique f64 argmax
        }
        buf ^= 1;
    }
    __syncthreads();
    for (int i = t; i < SCENT; i += FPS_T) {
        float* o = new_xyz + (size_t)(b * SCENT + i) * 3;
        o[0] = hx[i]; o[1] = hy[i]; o[2] = hz[i];
    }
}

// ---------------------------------------------------------------------------
// Kernel 2: transpose points (B,D,N) -> (B,N,D).
// ---------------------------------------------------------------------------
__global__ void transpose_kernel(const float* __restrict__ pts, float* __restrict__ out) {
    __shared__ float tile[32][33];
    const int b  = blockIdx.z;
    const int n0 = blockIdx.x * 32, d0 = blockIdx.y * 32;
    const int tx = threadIdx.x, ty = threadIdx.y;   // block (32,8)
#pragma unroll
    for (int i = 0; i < 4; ++i)
        tile[ty + 8 * i][tx] =
            pts[(size_t)b * DFEAT * NPTS + (size_t)(d0 + ty + 8 * i) * NPTS + n0 + tx];
    __syncthreads();
#pragma unroll
    for (int i = 0; i < 4; ++i)
        out[(size_t)b * NPTS * DFEAT + (size_t)(n0 + ty + 8 * i) * DFEAT + d0 + tx] =
            tile[tx][ty + 8 * i];
}

// ---------------------------------------------------------------------------
// Kernel 3: KNN, one WAVE per query (f64-exact ordering, wave-parallel sorted
// top-32 with ballot/shfl insertion).
// ---------------------------------------------------------------------------
__global__ __launch_bounds__(256) void knn_kernel(const float* __restrict__ xyz,
                                                  const float* __restrict__ new_xyz,
                                                  int* __restrict__ knn_idx) {
    const int b    = blockIdx.y;
    const int wid  = threadIdx.x >> 6;
    const int lane = threadIdx.x & 63;
    const int qi   = blockIdx.x * 4 + wid;

    __shared__ float4 sp[2048];
    __shared__ double sp2[2048];

    const float* q = new_xyz + (size_t)(b * SCENT + qi) * 3;
    const double qx = (double)q[0], qy = (double)q[1], qz = (double)q[2];
    const double q2 = __dadd_rn(__dadd_rn(__dmul_rn(qx, qx), __dmul_rn(qy, qy)),
                                __dmul_rn(qz, qz));

    double ld   = DBL_MAX;
    int    li   = 0x7fffffff;
    double taud = DBL_MAX;
    int    taui = 0x7fffffff;

    const float* Xb = xyz + (size_t)b * NPTS * 3;
#pragma unroll 1
    for (int c = 0; c < 4; ++c) {
        __syncthreads();
#pragma unroll
        for (int r = 0; r < 8; ++r) {
            int pl = r * 256 + threadIdx.x;
            int p  = c * 2048 + pl;
            float x = Xb[3 * p + 0], y = Xb[3 * p + 1], z = Xb[3 * p + 2];
            sp[pl] = make_float4(x, y, z, 0.0f);
            double dx = (double)x, dy = (double)y, dz = (double)z;
            sp2[pl] = __dadd_rn(__dadd_rn(__dmul_rn(dx, dx), __dmul_rn(dy, dy)),
                                __dmul_rn(dz, dz));
        }
        __syncthreads();
#pragma unroll 1
        for (int i = 0; i < 32; ++i) {
            const int pl   = i * 64 + lane;
            const int pidx = c * 2048 + pl;
            float4 P = sp[pl];
            double px = (double)P.x, py = (double)P.y, pz = (double)P.z;
            double qp = __dadd_rn(__dadd_rn(__dmul_rn(qx, px), __dmul_rn(qy, py)),
                                  __dmul_rn(qz, pz));
            double d  = __dsub_rn(__dadd_rn(q2, sp2[pl]), __dmul_rn(2.0, qp));
            bool cand = (d < taud) || (d == taud && pidx < taui);
            unsigned long long m = __ballot(cand);
            while (m) {
                int sl = __ffsll((unsigned long long)m) - 1;
                m &= m - 1;
                double dv = __shfl(d, sl);
                int    iv = __shfl(pidx, sl);
                if (dv < taud || (dv == taud && iv < taui)) {
                    bool gt = (lane < 32) && (ld > dv || (ld == dv && li > iv));
                    unsigned long long gm = __ballot(gt);
                    double ud = __shfl_up(ld, 1);
                    int    ui = __shfl_up(li, 1);
                    if (gt) { ld = ud; li = ui; }
                    bool first = gt && ((lane == 0) || !((gm >> (lane - 1)) & 1ull));
                    if (first) { ld = dv; li = iv; }
                    taud = __shfl(ld, 31);
                    taui = __shfl(li, 31);
                }
            }
        }
    }
    if (lane < 32) knn_idx[(size_t)(b * SCENT + qi) * KNEIGH + lane] = li;
}

// ---------------------------------------------------------------------------
// Kernel 4: gather + 3-layer MLP (BN folded, fp32) + max over K.
// ---------------------------------------------------------------------------
__global__ __launch_bounds__(256) void mlp_kernel(
    const float* __restrict__ xyz, const float* __restrict__ new_xyz,
    const float* __restrict__ ptsT, const int* __restrict__ knn_idx,
    const float* __restrict__ w0, const float* __restrict__ g0,
    const float* __restrict__ b0, const float* __restrict__ m0,
    const float* __restrict__ v0, const float* __restrict__ w1,
    const float* __restrict__ g1, const float* __restrict__ b1,
    const float* __restrict__ m1, const float* __restrict__ v1,
    const float* __restrict__ w2, const float* __restrict__ g2,
    const float* __restrict__ b2, const float* __restrict__ m2,
    const float* __restrict__ v2, float* __restrict__ out_points) {

    __shared__ float regA[8192];
    __shared__ float regB[4096];
    __shared__ float prm[512];

    const int t = threadIdx.x;
    if (t < 64) {
        float a0v = g0[t] / sqrtf(v0[t] + 1e-5f);
        prm[t]       = a0v;
        prm[64 + t]  = b0[t] - m0[t] * a0v;
        float a1v = g1[t] / sqrtf(v1[t] + 1e-5f);
        prm[128 + t] = a1v;
        prm[192 + t] = b1[t] - m1[t] * a1v;
    } else if (t < 192) {
        int o = t - 64;
        float a2v = g2[o] / sqrtf(v2[o] + 1e-5f);
        prm[256 + o] = a2v;
        prm[384 + o] = b2[o] - m2[o] * a2v;
    }
    for (int idx = t; idx < 64 * 68; idx += 256) {
        int o = idx / 68, i = idx - o * 68;
        float v;
        if (i < 64)      v = w0[o * 67 + 3 + i];
        else if (i < 67) v = w0[o * 67 + (i - 64)];
        else             v = 0.0f;
        regA[idx] = v;
    }
    for (int idx = t; idx < 64 * 64; idx += 256) regB[idx] = w1[idx];
    __syncthreads();

    const int gid = blockIdx.x * 256 + t;
    const int sl  = gid >> 5;
    const int s   = sl & (SCENT - 1);
    const int b   = sl >> 11;
    const int nidx = knn_idx[gid];

    const float* q  = new_xyz + (size_t)(b * SCENT + s) * 3;
    const float* P3 = xyz + (size_t)(b * NPTS + nidx) * 3;
    const float dx = P3[0] - q[0], dy = P3[1] - q[1], dz = P3[2] - q[2];

    const float4* F = (const float4*)(ptsT + ((size_t)b * NPTS + nidx) * 64);
    float4 xv[17];
#pragma unroll
    for (int i = 0; i < 16; ++i) xv[i] = F[i];
    xv[16] = make_float4(dx, dy, dz, 0.0f);

    float h0[64];
    const float4* W0 = (const float4*)regA;
#pragma unroll
    for (int o = 0; o < 64; ++o) {
        float acc = 0.f;
#pragma unroll
        for (int i = 0; i < 17; ++i) {
            float4 w = W0[o * 17 + i];
            acc = fmaf(xv[i].x, w.x, acc);
            acc = fmaf(xv[i].y, w.y, acc);
            acc = fmaf(xv[i].z, w.z, acc);
            acc = fmaf(xv[i].w, w.w, acc);
        }
        h0[o] = fmaxf(fmaf(acc, prm[o], prm[64 + o]), 0.f);
    }
    __syncthreads();
    for (int idx = t; idx < 128 * 64; idx += 256) regA[idx] = w2[idx];
    __syncthreads();

    float h1[64];
    const float4* W1 = (const float4*)regB;
#pragma unroll
    for (int o = 0; o < 64; ++o) {
        float acc = 0.f;
#pragma unroll
        for (int i = 0; i < 16; ++i) {
            float4 w = W1[o * 16 + i];
            acc = fmaf(h0[4 * i + 0], w.x, acc);
            acc = fmaf(h0[4 * i + 1], w.y, acc);
            acc = fmaf(h0[4 * i + 2], w.z, acc);
            acc = fmaf(h0[4 * i + 3], w.w, acc);
        }
        h1[o] = fmaxf(fmaf(acc, prm[128 + o], prm[192 + o]), 0.f);
    }

    const float4* W2 = (const float4*)regA;
    float* outp = out_points + (size_t)b * 128 * SCENT + s;
    const int lane = t & 63;
#pragma unroll 1
    for (int o = 0; o < 128; ++o) {
        float acc = 0.f;
#pragma unroll
        for (int i = 0; i < 16; ++i) {
            float4 w = W2[o * 16 + i];
            acc = fmaf(h1[4 * i + 0], w.x, acc);
            acc = fmaf(h1[4 * i + 1], w.y, acc);
            acc = fmaf(h1[4 * i + 2], w.z, acc);
            acc = fmaf(h1[4 * i + 3], w.w, acc);
        }
        float y = fmaxf(fmaf(acc, prm[256 + o], prm[384 + o]), 0.f);
#pragma unroll
        for (int off = 16; off >= 1; off >>= 1) y = fmaxf(y, __shfl_xor(y, off));
        if ((lane & 31) == 0) outp[(size_t)o * SCENT] = y;
    }
}

// ---------------------------------------------------------------------------
extern "C" void kernel_launch(void* const* d_in, const int* in_sizes, int n_in,
                              void* d_out, int out_size, void* d_ws, size_t ws_size,
                              hipStream_t stream) {
    const float* xyz    = (const float*)d_in[0];
    const float* points = (const float*)d_in[1];
    const float* w0 = (const float*)d_in[2];
    const float* g0 = (const float*)d_in[3];
    const float* b0 = (const float*)d_in[4];
    const float* m0 = (const float*)d_in[5];
    const float* v0 = (const float*)d_in[6];
    const float* w1 = (const float*)d_in[7];
    const float* g1 = (const float*)d_in[8];
    const float* b1 = (const float*)d_in[9];
    const float* m1 = (const float*)d_in[10];
    const float* v1 = (const float*)d_in[11];
    const float* w2 = (const float*)d_in[12];
    const float* g2 = (const float*)d_in[13];
    const float* b2 = (const float*)d_in[14];
    const float* m2 = (const float*)d_in[15];
    const float* v2 = (const float*)d_in[16];

    float* out_xyz    = (float*)d_out;                               // (B,S,3)
    float* out_points = (float*)d_out + (size_t)BATCH * SCENT * 3;   // (B,128,S)

    char* ws = (char*)d_ws;
    int*   knn_idx = (int*)(ws + 32768);
    float* ptsT    = (float*)(ws + 32768 + (size_t)BATCH * SCENT * KNEIGH * 4);

    fps_kernel<<<BATCH, FPS_T, 0, stream>>>(xyz, out_xyz);
    transpose_kernel<<<dim3(NPTS / 32, DFEAT / 32, BATCH), dim3(32, 8), 0, stream>>>(points, ptsT);
    knn_kernel<<<dim3(SCENT / 4, BATCH), 256, 0, stream>>>(xyz, out_xyz, knn_idx);
    mlp_kernel<<<(BATCH * SCENT * KNEIGH) / 256, 256, 0, stream>>>(
        xyz, out_xyz, ptsT, knn_idx,
        w0, g0, b0, m0, v0, w1, g1, b1, m1, v1, w2, g2, b2, m2, v2, out_points);
}

// Round 11
// 2696.762 us; speedup vs baseline: 1.0240x; 1.0240x over previous
//
#include <hip/hip_runtime.h>
#include <cfloat>
#include <climits>

#define NPTS   8192
#define SCENT  2048
#define KNEIGH 32
#define BATCH  4
#define DFEAT  64
#define FPS_T  512
#define NV     8       // v2f pairs per thread (16 points)
#define NW     8       // waves per block
#define CAP    64      // fallback candidate capacity

typedef float v2f __attribute__((ext_vector_type(2)));

// DPP max step over uint (positive-f32 bit pattern preserves order).
#define DPPMAX(u, ctrl, rmask)                                                        \
    { unsigned _t = (unsigned)__builtin_amdgcn_update_dpp(0, (int)(u), (ctrl),        \
                                                          (rmask), 0xf, false);      \
      (u) = ((u) > _t) ? (u) : _t; }

// ---------------------------------------------------------------------------
// Kernel 1: FPS. f32 fast path + exact-f64 fallback (proof as R3..R10: f32
// rounding keeps relative error << 2e-6; if no second point has dist32 >=
// v1*(1-2e-6) the f32 argmax IS the f64 argmax, and the fast path commits
// ONLY in that provably-unique case; otherwise candidates >= threshold are
// re-scored exactly in f64 vs the centroid history, lexicographic
// (d, original idx) = numpy argmax tie rule).
// R11 = R9 one-barrier chain + R10 packed math:
//   packed update w/ packed 2nd-max tracking -> DPP wave max -> eq-scan idx
//   -> ballots (tie rule == R6..R9) -> slot(wu, idx|tie) -> B1 -> 8-slot
//   merge -> coords from LDS point table.
// ---------------------------------------------------------------------------
__global__ __launch_bounds__(FPS_T, 1) void fps_kernel(const float* __restrict__ xyz,
                                                       float* __restrict__ new_xyz) {
    const int b = blockIdx.x, t = threadIdx.x;
    const int lane = t & 63, w = t >> 6;
    const float* X = xyz + (size_t)b * NPTS * 3;

    __shared__ float sx[NPTS], sy[NPTS], sz[NPTS];   // 96 KB point table
    __shared__ float hx[SCENT], hy[SCENT], hz[SCENT];// 24 KB centroid history
    __shared__ __align__(16) uint2 slots[2][NW];
    __shared__ int   scand[CAP];
    __shared__ int   scnt;
    __shared__ double sdd[2][NW];
    __shared__ double sfv[NW];
    __shared__ int   sfo[NW];

    for (int p = t; p < NPTS; p += FPS_T) {
        sx[p] = X[3 * p + 0]; sy[p] = X[3 * p + 1]; sz[p] = X[3 * p + 2];
    }

    v2f px2[NV], py2[NV], pz2[NV], dist2[NV];
#pragma unroll
    for (int j = 0; j < NV; ++j) {
        int pA = t + FPS_T * j, pB = t + FPS_T * (j + NV);
        px2[j] = (v2f){X[3 * pA + 0], X[3 * pB + 0]};
        py2[j] = (v2f){X[3 * pA + 1], X[3 * pB + 1]};
        pz2[j] = (v2f){X[3 * pA + 2], X[3 * pB + 2]};
        dist2[j] = (v2f){1e10f, 1e10f};
    }
    float cx = X[0], cy = X[1], cz = X[2];
    int buf = 0;
    __syncthreads();

#pragma unroll 1
    for (int s = 0; s < SCENT; ++s) {
        if (t == 0) { hx[s] = cx; hy[s] = cy; hz[s] = cz; }

        // ---- packed update + packed top-2 tracking ----
        const v2f cxx = {cx, cx}, cyy = {cy, cy}, czz = {cz, cz};
        v2f m2 = {-1.f, -1.f}, s2 = {-1.f, -1.f};
#pragma unroll
        for (int j = 0; j < NV; ++j) {
            v2f dx = px2[j] - cxx;
            v2f dy = py2[j] - cyy;
            v2f dz = pz2[j] - czz;
            v2f d  = __builtin_elementwise_fma(dx, dx,
                     __builtin_elementwise_fma(dy, dy, dz * dz));
            v2f nd = __builtin_elementwise_min(dist2[j], d);
            dist2[j] = nd;
            v2f lo = __builtin_elementwise_min(m2, nd);
            s2 = __builtin_elementwise_max(s2, lo);
            m2 = __builtin_elementwise_max(m2, nd);
        }
        const float m   = fmaxf(m2.x, m2.y);
        const float sec = fmaxf(fmaxf(s2.x, s2.y), fminf(m2.x, m2.y));

        // ---- lane argmax idx via equality scan (any match is fine: the fast
        //      path commits only on provably-unique winners) ----
        int mi = 0;
#pragma unroll
        for (int j = 0; j < NV; ++j) {
            mi = (dist2[j].x == m) ? (t + FPS_T * j)        : mi;
            mi = (dist2[j].y == m) ? (t + FPS_T * (j + NV)) : mi;
        }

        // ---- wave max via DPP (pure VALU) ----
        unsigned myU = __float_as_uint(m);
        unsigned u = myU;
        DPPMAX(u, 0x111, 0xf);   // row_shr:1
        DPPMAX(u, 0x112, 0xf);   // row_shr:2
        DPPMAX(u, 0x114, 0xf);   // row_shr:4
        DPPMAX(u, 0x118, 0xf);   // row_shr:8
        DPPMAX(u, 0x142, 0xa);   // row_bcast:15
        DPPMAX(u, 0x143, 0xc);   // row_bcast:31
        const unsigned wu = (unsigned)__builtin_amdgcn_readlane((int)u, 63);

        // ---- winner idx + tie flags (rule identical to R6..R9) ----
        unsigned long long wb = __ballot(myU == wu);
        const int wl   = __ffsll(wb) - 1;
        const int widx = __builtin_amdgcn_readlane(mi, wl);
        const float thwf = __fmul_rn(__uint_as_float(wu), 0.999998f);
        unsigned long long b1 = __ballot(m >= thwf);
        unsigned long long b2 = __ballot(sec >= thwf);
        const unsigned tw = (b2 || __popcll(b1) >= 2) ? 1u : 0u;
        if (lane == 0)
            slots[buf][w] = make_uint2(wu, (unsigned)widx | (tw << 14));
        __syncthreads();                                  // the ONE barrier

        // ---- redundant merge: 8 slots + umax tree ----
        uint2 sv[NW];
        {
            const uint4* sp = (const uint4*)&slots[buf][0];
            uint4 a = sp[0], c = sp[1], e = sp[2], f = sp[3];
            sv[0] = make_uint2(a.x, a.y); sv[1] = make_uint2(a.z, a.w);
            sv[2] = make_uint2(c.x, c.y); sv[3] = make_uint2(c.z, c.w);
            sv[4] = make_uint2(e.x, e.y); sv[5] = make_uint2(e.z, e.w);
            sv[6] = make_uint2(f.x, f.y); sv[7] = make_uint2(f.z, f.w);
        }
        unsigned gu = sv[0].x;
#pragma unroll
        for (int k = 1; k < NW; ++k) gu = (sv[k].x > gu) ? sv[k].x : gu;
        const float gvf  = __uint_as_float(gu);
        const float gthf = __fmul_rn(gvf, 0.999998f);
        const unsigned ugth = __float_as_uint(gthf);
        int nw = 0; unsigned meta = 0;
#pragma unroll
        for (int k = NW - 1; k >= 0; --k) {
            nw += (sv[k].x >= ugth) ? 1 : 0;
            meta = (sv[k].x == gu) ? sv[k].y : meta;
        }
        const int wtie = (meta >> 14) & 1;
        int i1 = (int)(meta & 0x3fffu);

        if (nw >= 2 || wtie) {
            // ---- exact f64 fallback (block-uniform, rare) ----
            if (t == 0) scnt = 0;
            __syncthreads();
#pragma unroll
            for (int j = 0; j < NV; ++j) {
                if (dist2[j].x >= gthf) {
                    int slot = atomicAdd(&scnt, 1);
                    if (slot < CAP) scand[slot] = t + FPS_T * j;
                }
                if (dist2[j].y >= gthf) {
                    int slot = atomicAdd(&scnt, 1);
                    if (slot < CAP) scand[slot] = t + FPS_T * (j + NV);
                }
            }
            __syncthreads();
            const int mm = scnt;
            if (mm <= CAP) {
                double bd = -1.0; int bi = INT_MAX;
#pragma unroll 1
                for (int k = 0; k < mm; ++k) {
                    const int pos = scand[k];
                    const double pxd = (double)sx[pos], pyd = (double)sy[pos],
                                 pzd = (double)sz[pos];
                    double dd = 1e10;
                    for (int i = t; i <= s; i += FPS_T) {
                        double ddx = __dsub_rn(pxd, (double)hx[i]);
                        double ddy = __dsub_rn(pyd, (double)hy[i]);
                        double ddz = __dsub_rn(pzd, (double)hz[i]);
                        double d = __dadd_rn(__dadd_rn(__dmul_rn(ddx, ddx), __dmul_rn(ddy, ddy)),
                                             __dmul_rn(ddz, ddz));
                        dd = fmin(dd, d);
                    }
#pragma unroll
                    for (int off = 32; off >= 1; off >>= 1)
                        dd = fmin(dd, __shfl_down(dd, off));
                    if (lane == 0) sdd[k & 1][w] = dd;
                    __syncthreads();
                    double ddm = sdd[k & 1][0];
#pragma unroll
                    for (int w2 = 1; w2 < NW; ++w2) ddm = fmin(ddm, sdd[k & 1][w2]);
                    if (ddm > bd || (ddm == bd && pos < bi)) { bd = ddm; bi = pos; }
                }
                i1 = bi;
            } else {
                // safety net: full exact scan (practically unreachable)
                double bv = -1.0; int bi = INT_MAX;
#pragma unroll 1
                for (int j = 0; j < 2 * NV; ++j) {
                    const int jj = j & (NV - 1);
                    const bool hiHalf = j >= NV;
                    const double pxd = (double)(hiHalf ? px2[jj].y : px2[jj].x);
                    const double pyd = (double)(hiHalf ? py2[jj].y : py2[jj].x);
                    const double pzd = (double)(hiHalf ? pz2[jj].y : pz2[jj].x);
                    double dd = 1e10;
                    for (int i = 0; i <= s; ++i) {
                        double ddx = __dsub_rn(pxd, (double)hx[i]);
                        double ddy = __dsub_rn(pyd, (double)hy[i]);
                        double ddz = __dsub_rn(pzd, (double)hz[i]);
                        double d = __dadd_rn(__dadd_rn(__dmul_rn(ddx, ddx), __dmul_rn(ddy, ddy)),
                                             __dmul_rn(ddz, ddz));
                        dd = fmin(dd, d);
                    }
                    int pidx = t + FPS_T * j;
                    if (dd > bv || (dd == bv && pidx < bi)) { bv = dd; bi = pidx; }
                }
#pragma unroll
                for (int off = 32; off >= 1; off >>= 1) {
                    double ov = __shfl_down(bv, off);
                    int    oi = __shfl_down(bi, off);
                    if (ov > bv || (ov == bv && oi < bi)) { bv = ov; bi = oi; }
                }
                if (lane == 0) { sfv[w] = bv; sfo[w] = bi; }
                __syncthreads();
                bv = sfv[0]; bi = sfo[0];
#pragma unroll
                for (int w2 = 1; w2 < NW; ++w2) {
                    double ov = sfv[w2]; int oi = sfo[w2];
                    if (ov > bv || (ov == bv && oi < bi)) { bv = ov; bi = oi; }
                }
                i1 = bi;
            }
            __syncthreads();
        }
        cx = sx[i1]; cy = sy[i1]; cz = sz[i1];    // broadcast LDS reads
        buf ^= 1;
    }
    __syncthreads();
    for (int i = t; i < SCENT; i += FPS_T) {
        float* o = new_xyz + (size_t)(b * SCENT + i) * 3;
        o[0] = hx[i]; o[1] = hy[i]; o[2] = hz[i];
    }
}

// ---------------------------------------------------------------------------
// Kernel 2: transpose points (B,D,N) -> (B,N,D).
// ---------------------------------------------------------------------------
__global__ void transpose_kernel(const float* __restrict__ pts, float* __restrict__ out) {
    __shared__ float tile[32][33];
    const int b  = blockIdx.z;
    const int n0 = blockIdx.x * 32, d0 = blockIdx.y * 32;
    const int tx = threadIdx.x, ty = threadIdx.y;   // block (32,8)
#pragma unroll
    for (int i = 0; i < 4; ++i)
        tile[ty + 8 * i][tx] =
            pts[(size_t)b * DFEAT * NPTS + (size_t)(d0 + ty + 8 * i) * NPTS + n0 + tx];
    __syncthreads();
#pragma unroll
    for (int i = 0; i < 4; ++i)
        out[(size_t)b * NPTS * DFEAT + (size_t)(n0 + ty + 8 * i) * DFEAT + d0 + tx] =
            tile[tx][ty + 8 * i];
}

// ---------------------------------------------------------------------------
// Kernel 3: KNN, one WAVE per query (f64-exact ordering, wave-parallel sorted
// top-32 with ballot/shfl insertion).
// ---------------------------------------------------------------------------
__global__ __launch_bounds__(256) void knn_kernel(const float* __restrict__ xyz,
                                                  const float* __restrict__ new_xyz,
                                                  int* __restrict__ knn_idx) {
    const int b    = blockIdx.y;
    const int wid  = threadIdx.x >> 6;
    const int lane = threadIdx.x & 63;
    const int qi   = blockIdx.x * 4 + wid;

    __shared__ float4 sp[2048];
    __shared__ double sp2[2048];

    const float* q = new_xyz + (size_t)(b * SCENT + qi) * 3;
    const double qx = (double)q[0], qy = (double)q[1], qz = (double)q[2];
    const double q2 = __dadd_rn(__dadd_rn(__dmul_rn(qx, qx), __dmul_rn(qy, qy)),
                                __dmul_rn(qz, qz));

    double ld   = DBL_MAX;
    int    li   = 0x7fffffff;
    double taud = DBL_MAX;
    int    taui = 0x7fffffff;

    const float* Xb = xyz + (size_t)b * NPTS * 3;
#pragma unroll 1
    for (int c = 0; c < 4; ++c) {
        __syncthreads();
#pragma unroll
        for (int r = 0; r < 8; ++r) {
            int pl = r * 256 + threadIdx.x;
            int p  = c * 2048 + pl;
            float x = Xb[3 * p + 0], y = Xb[3 * p + 1], z = Xb[3 * p + 2];
            sp[pl] = make_float4(x, y, z, 0.0f);
            double dx = (double)x, dy = (double)y, dz = (double)z;
            sp2[pl] = __dadd_rn(__dadd_rn(__dmul_rn(dx, dx), __dmul_rn(dy, dy)),
                                __dmul_rn(dz, dz));
        }
        __syncthreads();
#pragma unroll 1
        for (int i = 0; i < 32; ++i) {
            const int pl   = i * 64 + lane;
            const int pidx = c * 2048 + pl;
            float4 P = sp[pl];
            double px = (double)P.x, py = (double)P.y, pz = (double)P.z;
            double qp = __dadd_rn(__dadd_rn(__dmul_rn(qx, px), __dmul_rn(qy, py)),
                                  __dmul_rn(qz, pz));
            double d  = __dsub_rn(__dadd_rn(q2, sp2[pl]), __dmul_rn(2.0, qp));
            bool cand = (d < taud) || (d == taud && pidx < taui);
            unsigned long long m = __ballot(cand);
            while (m) {
                int sl = __ffsll((unsigned long long)m) - 1;
                m &= m - 1;
                double dv = __shfl(d, sl);
                int    iv = __shfl(pidx, sl);
                if (dv < taud || (dv == taud && iv < taui)) {
                    bool gt = (lane < 32) && (ld > dv || (ld == dv && li > iv));
                    unsigned long long gm = __ballot(gt);
                    double ud = __shfl_up(ld, 1);
                    int    ui = __shfl_up(li, 1);
                    if (gt) { ld = ud; li = ui; }
                    bool first = gt && ((lane == 0) || !((gm >> (lane - 1)) & 1ull));
                    if (first) { ld = dv; li = iv; }
                    taud = __shfl(ld, 31);
                    taui = __shfl(li, 31);
                }
            }
        }
    }
    if (lane < 32) knn_idx[(size_t)(b * SCENT + qi) * KNEIGH + lane] = li;
}

// ---------------------------------------------------------------------------
// Kernel 4: gather + 3-layer MLP (BN folded, fp32) + max over K.
// ---------------------------------------------------------------------------
__global__ __launch_bounds__(256) void mlp_kernel(
    const float* __restrict__ xyz, const float* __restrict__ new_xyz,
    const float* __restrict__ ptsT, const int* __restrict__ knn_idx,
    const float* __restrict__ w0, const float* __restrict__ g0,
    const float* __restrict__ b0, const float* __restrict__ m0,
    const float* __restrict__ v0, const float* __restrict__ w1,
    const float* __restrict__ g1, const float* __restrict__ b1,
    const float* __restrict__ m1, const float* __restrict__ v1,
    const float* __restrict__ w2, const float* __restrict__ g2,
    const float* __restrict__ b2, const float* __restrict__ m2,
    const float* __restrict__ v2, float* __restrict__ out_points) {

    __shared__ float regA[8192];
    __shared__ float regB[4096];
    __shared__ float prm[512];

    const int t = threadIdx.x;
    if (t < 64) {
        float a0v = g0[t] / sqrtf(v0[t] + 1e-5f);
        prm[t]       = a0v;
        prm[64 + t]  = b0[t] - m0[t] * a0v;
        float a1v = g1[t] / sqrtf(v1[t] + 1e-5f);
        prm[128 + t] = a1v;
        prm[192 + t] = b1[t] - m1[t] * a1v;
    } else if (t < 192) {
        int o = t - 64;
        float a2v = g2[o] / sqrtf(v2[o] + 1e-5f);
        prm[256 + o] = a2v;
        prm[384 + o] = b2[o] - m2[o] * a2v;
    }
    for (int idx = t; idx < 64 * 68; idx += 256) {
        int o = idx / 68, i = idx - o * 68;
        float v;
        if (i < 64)      v = w0[o * 67 + 3 + i];
        else if (i < 67) v = w0[o * 67 + (i - 64)];
        else             v = 0.0f;
        regA[idx] = v;
    }
    for (int idx = t; idx < 64 * 64; idx += 256) regB[idx] = w1[idx];
    __syncthreads();

    const int gid = blockIdx.x * 256 + t;
    const int sl  = gid >> 5;
    const int s   = sl & (SCENT - 1);
    const int b   = sl >> 11;
    const int nidx = knn_idx[gid];

    const float* q  = new_xyz + (size_t)(b * SCENT + s) * 3;
    const float* P3 = xyz + (size_t)(b * NPTS + nidx) * 3;
    const float dx = P3[0] - q[0], dy = P3[1] - q[1], dz = P3[2] - q[2];

    const float4* F = (const float4*)(ptsT + ((size_t)b * NPTS + nidx) * 64);
    float4 xv[17];
#pragma unroll
    for (int i = 0; i < 16; ++i) xv[i] = F[i];
    xv[16] = make_float4(dx, dy, dz, 0.0f);

    float h0[64];
    const float4* W0 = (const float4*)regA;
#pragma unroll
    for (int o = 0; o < 64; ++o) {
        float acc = 0.f;
#pragma unroll
        for (int i = 0; i < 17; ++i) {
            float4 w = W0[o * 17 + i];
            acc = fmaf(xv[i].x, w.x, acc);
            acc = fmaf(xv[i].y, w.y, acc);
            acc = fmaf(xv[i].z, w.z, acc);
            acc = fmaf(xv[i].w, w.w, acc);
        }
        h0[o] = fmaxf(fmaf(acc, prm[o], prm[64 + o]), 0.f);
    }
    __syncthreads();
    for (int idx = t; idx < 128 * 64; idx += 256) regA[idx] = w2[idx];
    __syncthreads();

    float h1[64];
    const float4* W1 = (const float4*)regB;
#pragma unroll
    for (int o = 0; o < 64; ++o) {
        float acc = 0.f;
#pragma unroll
        for (int i = 0; i < 16; ++i) {
            float4 w = W1[o * 16 + i];
            acc = fmaf(h0[4 * i + 0], w.x, acc);
            acc = fmaf(h0[4 * i + 1], w.y, acc);
            acc = fmaf(h0[4 * i + 2], w.z, acc);
            acc = fmaf(h0[4 * i + 3], w.w, acc);
        }
        h1[o] = fmaxf(fmaf(acc, prm[128 + o], prm[192 + o]), 0.f);
    }

    const float4* W2 = (const float4*)regA;
    float* outp = out_points + (size_t)b * 128 * SCENT + s;
    const int lane = t & 63;
#pragma unroll 1
    for (int o = 0; o < 128; ++o) {
        float acc = 0.f;
#pragma unroll
        for (int i = 0; i < 16; ++i) {
            float4 w = W2[o * 16 + i];
            acc = fmaf(h1[4 * i + 0], w.x, acc);
            acc = fmaf(h1[4 * i + 1], w.y, acc);
            acc = fmaf(h1[4 * i + 2], w.z, acc);
            acc = fmaf(h1[4 * i + 3], w.w, acc);
        }
        float y = fmaxf(fmaf(acc, prm[256 + o], prm[384 + o]), 0.f);
#pragma unroll
        for (int off = 16; off >= 1; off >>= 1) y = fmaxf(y, __shfl_xor(y, off));
        if ((lane & 31) == 0) outp[(size_t)o * SCENT] = y;
    }
}

// ---------------------------------------------------------------------------
extern "C" void kernel_launch(void* const* d_in, const int* in_sizes, int n_in,
                              void* d_out, int out_size, void* d_ws, size_t ws_size,
                              hipStream_t stream) {
    const float* xyz    = (const float*)d_in[0];
    const float* points = (const float*)d_in[1];
    const float* w0 = (const float*)d_in[2];
    const float* g0 = (const float*)d_in[3];
    const float* b0 = (const float*)d_in[4];
    const float* m0 = (const float*)d_in[5];
    const float* v0 = (const float*)d_in[6];
    const float* w1 = (const float*)d_in[7];
    const float* g1 = (const float*)d_in[8];
    const float* b1 = (const float*)d_in[9];
    const float* m1 = (const float*)d_in[10];
    const float* v1 = (const float*)d_in[11];
    const float* w2 = (const float*)d_in[12];
    const float* g2 = (const float*)d_in[13];
    const float* b2 = (const float*)d_in[14];
    const float* m2 = (const float*)d_in[15];
    const float* v2 = (const float*)d_in[16];

    float* out_xyz    = (float*)d_out;                               // (B,S,3)
    float* out_points = (float*)d_out + (size_t)BATCH * SCENT * 3;   // (B,128,S)

    char* ws = (char*)d_ws;
    int*   knn_idx = (int*)(ws + 32768);
    float* ptsT    = (float*)(ws + 32768 + (size_t)BATCH * SCENT * KNEIGH * 4);

    fps_kernel<<<BATCH, FPS_T, 0, stream>>>(xyz, out_xyz);
    transpose_kernel<<<dim3(NPTS / 32, DFEAT / 32, BATCH), dim3(32, 8), 0, stream>>>(points, ptsT);
    knn_kernel<<<dim3(SCENT / 4, BATCH), 256, 0, stream>>>(xyz, out_xyz, knn_idx);
    mlp_kernel<<<(BATCH * SCENT * KNEIGH) / 256, 256, 0, stream>>>(
        xyz, out_xyz, ptsT, knn_idx,
        w0, g0, b0, m0, v0, w1, g1, b1, m1, v1, w2, g2, b2, m2, v2, out_points);
}

// Round 12
// 2596.448 us; speedup vs baseline: 1.0635x; 1.0386x over previous
//
#include <hip/hip_runtime.h>
#include <cfloat>
#include <climits>

#define NPTS   8192
#define SCENT  2048
#define KNEIGH 32
#define BATCH  4
#define DFEAT  64
#define FPS_T  512
#define NV     8       // v2f pairs per thread (16 points)
#define NW     8       // waves per block
#define CAP    64      // fallback candidate capacity
#define NCONS  252     // consumer blocks
#define CPB    63      // consumer blocks per batch

typedef float v2f __attribute__((ext_vector_type(2)));

// DPP max step over uint (positive-f32 bit pattern preserves order).
#define DPPMAX(u, ctrl, rmask)                                                        \
    { unsigned _t = (unsigned)__builtin_amdgcn_update_dpp(0, (int)(u), (ctrl),        \
                                                          (rmask), 0xf, false);      \
      (u) = ((u) > _t) ? (u) : _t; }

struct FpsSh {                       // ~123.5 KB
    float sx[NPTS], sy[NPTS], sz[NPTS];
    float hx[SCENT], hy[SCENT], hz[SCENT];
    alignas(16) unsigned slotV[2][NW];
    alignas(16) unsigned slotM[2][NW];
    int scand[CAP];
    int scnt;
    alignas(8) double sdd[2][NW];
    double sfv[NW];
    int sfo[NW];
};
struct KnnSh {                       // ~45 KB
    float  spx[2048], spy[2048], spz[2048];
    double sp2[2048];
    float  tile[32 * 33];
};
union ShU { FpsSh f; KnnSh k; };

// ---------------------------------------------------------------------------
// Fused cooperative kernel. Blocks 0..3: FPS (R11 structure: packed update,
// DPP wave max, one barrier, f32 fast path + exact-f64 fallback — proof as
// R3..R11). New: every 64 centroids flush to global new_xyz (agent-scope
// relaxed stores, drained by the pre-barrier vmcnt(0)) then release-publish
// progress[b]. Blocks 4..255: transpose slice, then wave-per-query f64-exact
// KNN gated by acquire-spin on progress (queries in increasing s => overlap).
// Cooperative launch guarantees co-residency (1 block/CU via 123 KB LDS).
// ---------------------------------------------------------------------------
__global__ __launch_bounds__(FPS_T, 1) void fused_kernel(
        const float* __restrict__ xyz, float* __restrict__ new_xyz,
        const float* __restrict__ pts, float* __restrict__ ptsT,
        int* __restrict__ knn_idx, int* __restrict__ progress) {
    __shared__ ShU sh;
    const int t = threadIdx.x;
    const int lane = t & 63, w = t >> 6;

    if (blockIdx.x < BATCH) {
        // ==================== FPS producer ====================
        FpsSh& S = sh.f;
        const int b = blockIdx.x;
        const float* X = xyz + (size_t)b * NPTS * 3;

        for (int p = t; p < NPTS; p += FPS_T) {
            S.sx[p] = X[3 * p + 0]; S.sy[p] = X[3 * p + 1]; S.sz[p] = X[3 * p + 2];
        }

        v2f px2[NV], py2[NV], pz2[NV], dist2[NV];
#pragma unroll
        for (int j = 0; j < NV; ++j) {
            int pA = t + FPS_T * j, pB = t + FPS_T * (j + NV);
            px2[j] = (v2f){X[3 * pA + 0], X[3 * pB + 0]};
            py2[j] = (v2f){X[3 * pA + 1], X[3 * pB + 1]};
            pz2[j] = (v2f){X[3 * pA + 2], X[3 * pB + 2]};
            dist2[j] = (v2f){1e10f, 1e10f};
        }
        float cx = X[0], cy = X[1], cz = X[2];
        int buf = 0;
        __syncthreads();

#pragma unroll 1
        for (int s = 0; s < SCENT; ++s) {
            if (t == 0) { S.hx[s] = cx; S.hy[s] = cy; S.hz[s] = cz; }

            // ---- packed update + packed top-2 tracking ----
            const v2f cxx = {cx, cx}, cyy = {cy, cy}, czz = {cz, cz};
            v2f m2 = {-1.f, -1.f}, s2 = {-1.f, -1.f};
#pragma unroll
            for (int j = 0; j < NV; ++j) {
                v2f dx = px2[j] - cxx;
                v2f dy = py2[j] - cyy;
                v2f dz = pz2[j] - czz;
                v2f d  = __builtin_elementwise_fma(dx, dx,
                         __builtin_elementwise_fma(dy, dy, dz * dz));
                v2f nd = __builtin_elementwise_min(dist2[j], d);
                dist2[j] = nd;
                v2f lo = __builtin_elementwise_min(m2, nd);
                s2 = __builtin_elementwise_max(s2, lo);
                m2 = __builtin_elementwise_max(m2, nd);
            }
            const float m   = fmaxf(m2.x, m2.y);
            const float sec = fmaxf(fmaxf(s2.x, s2.y), fminf(m2.x, m2.y));

            int mi = 0;
#pragma unroll
            for (int j = 0; j < NV; ++j) {
                mi = (dist2[j].x == m) ? (t + FPS_T * j)        : mi;
                mi = (dist2[j].y == m) ? (t + FPS_T * (j + NV)) : mi;
            }

            unsigned myU = __float_as_uint(m);
            unsigned u = myU;
            DPPMAX(u, 0x111, 0xf);
            DPPMAX(u, 0x112, 0xf);
            DPPMAX(u, 0x114, 0xf);
            DPPMAX(u, 0x118, 0xf);
            DPPMAX(u, 0x142, 0xa);
            DPPMAX(u, 0x143, 0xc);
            const unsigned wu = (unsigned)__builtin_amdgcn_readlane((int)u, 63);

            unsigned long long wb = __ballot(myU == wu);
            const int wl   = __ffsll(wb) - 1;
            const int widx = __builtin_amdgcn_readlane(mi, wl);
            const float thwf = __fmul_rn(__uint_as_float(wu), 0.999998f);
            unsigned long long b1m = __ballot(m >= thwf);
            unsigned long long b2m = __ballot(sec >= thwf);
            const unsigned tw = (b2m || __popcll(b1m) >= 2) ? 1u : 0u;
            if (lane == 0) {
                S.slotV[buf][w] = wu;
                S.slotM[buf][w] = (unsigned)widx | (tw << 14);
            }
            __syncthreads();                                  // the ONE barrier

            unsigned sv[NW], sm[NW];
            {
                const uint4* vp = (const uint4*)&S.slotV[buf][0];
                const uint4* mp = (const uint4*)&S.slotM[buf][0];
                uint4 a = vp[0], c = vp[1], e = mp[0], f = mp[1];
                sv[0] = a.x; sv[1] = a.y; sv[2] = a.z; sv[3] = a.w;
                sv[4] = c.x; sv[5] = c.y; sv[6] = c.z; sv[7] = c.w;
                sm[0] = e.x; sm[1] = e.y; sm[2] = e.z; sm[3] = e.w;
                sm[4] = f.x; sm[5] = f.y; sm[6] = f.z; sm[7] = f.w;
            }
            unsigned gu = sv[0];
#pragma unroll
            for (int k = 1; k < NW; ++k) gu = (sv[k] > gu) ? sv[k] : gu;
            const float gvf  = __uint_as_float(gu);
            const float gthf = __fmul_rn(gvf, 0.999998f);
            const unsigned ugth = __float_as_uint(gthf);
            int nw = 0; unsigned meta = 0;
#pragma unroll
            for (int k = NW - 1; k >= 0; --k) {
                nw += (sv[k] >= ugth) ? 1 : 0;
                meta = (sv[k] == gu) ? sm[k] : meta;
            }
            const int wtie = (meta >> 14) & 1;
            int i1 = (int)(meta & 0x3fffu);

            if (nw >= 2 || wtie) {
                // ---- exact f64 fallback (block-uniform, rare) ----
                if (t == 0) S.scnt = 0;
                __syncthreads();
#pragma unroll
                for (int j = 0; j < NV; ++j) {
                    if (dist2[j].x >= gthf) {
                        int slot = atomicAdd(&S.scnt, 1);
                        if (slot < CAP) S.scand[slot] = t + FPS_T * j;
                    }
                    if (dist2[j].y >= gthf) {
                        int slot = atomicAdd(&S.scnt, 1);
                        if (slot < CAP) S.scand[slot] = t + FPS_T * (j + NV);
                    }
                }
                __syncthreads();
                const int mm = S.scnt;
                if (mm <= CAP) {
                    double bd = -1.0; int bi = INT_MAX;
#pragma unroll 1
                    for (int k = 0; k < mm; ++k) {
                        const int pos = S.scand[k];
                        const double pxd = (double)S.sx[pos], pyd = (double)S.sy[pos],
                                     pzd = (double)S.sz[pos];
                        double dd = 1e10;
                        for (int i = t; i <= s; i += FPS_T) {
                            double ddx = __dsub_rn(pxd, (double)S.hx[i]);
                            double ddy = __dsub_rn(pyd, (double)S.hy[i]);
                            double ddz = __dsub_rn(pzd, (double)S.hz[i]);
                            double d = __dadd_rn(__dadd_rn(__dmul_rn(ddx, ddx), __dmul_rn(ddy, ddy)),
                                                 __dmul_rn(ddz, ddz));
                            dd = fmin(dd, d);
                        }
#pragma unroll
                        for (int off = 32; off >= 1; off >>= 1)
                            dd = fmin(dd, __shfl_down(dd, off));
                        if (lane == 0) S.sdd[k & 1][w] = dd;
                        __syncthreads();
                        double ddm = S.sdd[k & 1][0];
#pragma unroll
                        for (int w2 = 1; w2 < NW; ++w2) ddm = fmin(ddm, S.sdd[k & 1][w2]);
                        if (ddm > bd || (ddm == bd && pos < bi)) { bd = ddm; bi = pos; }
                    }
                    i1 = bi;
                } else {
                    // safety net: full exact scan (practically unreachable)
                    double bv = -1.0; int bi = INT_MAX;
#pragma unroll 1
                    for (int j = 0; j < 2 * NV; ++j) {
                        const int jj = j & (NV - 1);
                        const bool hiHalf = j >= NV;
                        const double pxd = (double)(hiHalf ? px2[jj].y : px2[jj].x);
                        const double pyd = (double)(hiHalf ? py2[jj].y : py2[jj].x);
                        const double pzd = (double)(hiHalf ? pz2[jj].y : pz2[jj].x);
                        double dd = 1e10;
                        for (int i = 0; i <= s; ++i) {
                            double ddx = __dsub_rn(pxd, (double)S.hx[i]);
                            double ddy = __dsub_rn(pyd, (double)S.hy[i]);
                            double ddz = __dsub_rn(pzd, (double)S.hz[i]);
                            double d = __dadd_rn(__dadd_rn(__dmul_rn(ddx, ddx), __dmul_rn(ddy, ddy)),
                                                 __dmul_rn(ddz, ddz));
                            dd = fmin(dd, d);
                        }
                        int pidx = t + FPS_T * j;
                        if (dd > bv || (dd == bv && pidx < bi)) { bv = dd; bi = pidx; }
                    }
#pragma unroll
                    for (int off = 32; off >= 1; off >>= 1) {
                        double ov = __shfl_down(bv, off);
                        int    oi = __shfl_down(bi, off);
                        if (ov > bv || (ov == bv && oi < bi)) { bv = ov; bi = oi; }
                    }
                    if (lane == 0) { S.sfv[w] = bv; S.sfo[w] = bi; }
                    __syncthreads();
                    bv = S.sfv[0]; bi = S.sfo[0];
#pragma unroll
                    for (int w2 = 1; w2 < NW; ++w2) {
                        double ov = S.sfv[w2]; int oi = S.sfo[w2];
                        if (ov > bv || (ov == bv && oi < bi)) { bv = ov; bi = oi; }
                    }
                    i1 = bi;
                }
                __syncthreads();
            }
            cx = S.sx[i1]; cy = S.sy[i1]; cz = S.sz[i1];

            // ---- chunked flush + release publish every 64 centroids ----
            if ((s & 63) == 63) {
                const int base0 = s - 63;
                if (t < 64 * 3) {
                    int ci = base0 + t / 3;
                    int cmp = t - (t / 3) * 3;
                    float v = (cmp == 0) ? S.hx[ci] : ((cmp == 1) ? S.hy[ci] : S.hz[ci]);
                    __hip_atomic_store(&new_xyz[((size_t)b * SCENT + base0) * 3 + t], v,
                                       __ATOMIC_RELAXED, __HIP_MEMORY_SCOPE_AGENT);
                }
                __syncthreads();   // vmcnt(0) drain => stores device-visible
                if (t == 0)
                    __hip_atomic_store(&progress[b], s + 1,
                                       __ATOMIC_RELEASE, __HIP_MEMORY_SCOPE_AGENT);
            }
            buf ^= 1;
        }
    } else {
        // ==================== consumers: transpose + gated KNN ====================
        KnnSh& K = sh.k;
        const int local = blockIdx.x - BATCH;     // 0..251
        const int batch = local / CPB;            // 0..3
        const int cl    = local % CPB;            // 0..62
        const int tx = t & 31, ty = t >> 5;       // ty 0..15

        // ---- transpose slice: (B,D,N) -> (B,N,D), 32x32 tiles ----
        for (int tid2 = local; tid2 < 2048; tid2 += NCONS) {
            const int bt = tid2 >> 9, rest = tid2 & 511;
            const int d0 = (rest >> 8) * 32, n0 = (rest & 255) * 32;
            __syncthreads();
#pragma unroll
            for (int i = 0; i < 2; ++i)
                K.tile[(ty + 16 * i) * 33 + tx] =
                    pts[(size_t)bt * DFEAT * NPTS + (size_t)(d0 + ty + 16 * i) * NPTS + n0 + tx];
            __syncthreads();
#pragma unroll
            for (int i = 0; i < 2; ++i)
                ptsT[(size_t)bt * NPTS * DFEAT + (size_t)(n0 + ty + 16 * i) * DFEAT + d0 + tx] =
                    K.tile[tx * 33 + ty + 16 * i];
        }

        // ---- gated KNN rounds (increasing s => overlap with producer) ----
        const float* Xb = xyz + (size_t)batch * NPTS * 3;
#pragma unroll 1
        for (int r = 0; ; ++r) {
            const int sBase = r * (CPB * NW) + cl * NW;
            if (sBase >= SCENT) break;
            const int sMax = min(sBase + NW - 1, SCENT - 1);
            if (t == 0) {
                while (__hip_atomic_load(&progress[batch], __ATOMIC_ACQUIRE,
                                         __HIP_MEMORY_SCOPE_AGENT) < sMax + 1)
                    __builtin_amdgcn_s_sleep(8);
            }
            __syncthreads();

            const int sQ = min(sBase + w, SCENT - 1);
            const float* q = new_xyz + ((size_t)batch * SCENT + sQ) * 3;
            const double qx = (double)q[0], qy = (double)q[1], qz = (double)q[2];
            const double q2 = __dadd_rn(__dadd_rn(__dmul_rn(qx, qx), __dmul_rn(qy, qy)),
                                        __dmul_rn(qz, qz));

            double ld   = DBL_MAX;
            int    li   = 0x7fffffff;
            double taud = DBL_MAX;
            int    taui = 0x7fffffff;

#pragma unroll 1
            for (int c = 0; c < 4; ++c) {
                __syncthreads();
#pragma unroll
                for (int r2 = 0; r2 < 4; ++r2) {
                    int pl = r2 * 512 + t;
                    int p  = c * 2048 + pl;
                    float x = Xb[3 * p + 0], y = Xb[3 * p + 1], z = Xb[3 * p + 2];
                    K.spx[pl] = x; K.spy[pl] = y; K.spz[pl] = z;
                    double dx = (double)x, dy = (double)y, dz = (double)z;
                    K.sp2[pl] = __dadd_rn(__dadd_rn(__dmul_rn(dx, dx), __dmul_rn(dy, dy)),
                                          __dmul_rn(dz, dz));
                }
                __syncthreads();
#pragma unroll 1
                for (int i = 0; i < 32; ++i) {
                    const int pl   = i * 64 + lane;
                    const int pidx = c * 2048 + pl;
                    double px = (double)K.spx[pl], py = (double)K.spy[pl],
                           pz = (double)K.spz[pl];
                    double qp = __dadd_rn(__dadd_rn(__dmul_rn(qx, px), __dmul_rn(qy, py)),
                                          __dmul_rn(qz, pz));
                    double d  = __dsub_rn(__dadd_rn(q2, K.sp2[pl]), __dmul_rn(2.0, qp));
                    bool cand = (d < taud) || (d == taud && pidx < taui);
                    unsigned long long mmask = __ballot(cand);
                    while (mmask) {
                        int sl = __ffsll((unsigned long long)mmask) - 1;
                        mmask &= mmask - 1;
                        double dv = __shfl(d, sl);
                        int    iv = __shfl(pidx, sl);
                        if (dv < taud || (dv == taud && iv < taui)) {
                            bool gt = (lane < 32) && (ld > dv || (ld == dv && li > iv));
                            unsigned long long gm = __ballot(gt);
                            double ud = __shfl_up(ld, 1);
                            int    ui = __shfl_up(li, 1);
                            if (gt) { ld = ud; li = ui; }
                            bool first = gt && ((lane == 0) || !((gm >> (lane - 1)) & 1ull));
                            if (first) { ld = dv; li = iv; }
                            taud = __shfl(ld, 31);
                            taui = __shfl(li, 31);
                        }
                    }
                }
            }
            if (sBase + w < SCENT && lane < 32)
                knn_idx[((size_t)batch * SCENT + sQ) * KNEIGH + lane] = li;
        }
    }
}

// ---------------------------------------------------------------------------
// MLP kernel: gather + 3-layer MLP (BN folded, fp32) + max over K.
// ---------------------------------------------------------------------------
__global__ __launch_bounds__(256) void mlp_kernel(
    const float* __restrict__ xyz, const float* __restrict__ new_xyz,
    const float* __restrict__ ptsT, const int* __restrict__ knn_idx,
    const float* __restrict__ w0, const float* __restrict__ g0,
    const float* __restrict__ b0, const float* __restrict__ m0,
    const float* __restrict__ v0, const float* __restrict__ w1,
    const float* __restrict__ g1, const float* __restrict__ b1,
    const float* __restrict__ m1, const float* __restrict__ v1,
    const float* __restrict__ w2, const float* __restrict__ g2,
    const float* __restrict__ b2, const float* __restrict__ m2,
    const float* __restrict__ v2, float* __restrict__ out_points) {

    __shared__ float regA[8192];
    __shared__ float regB[4096];
    __shared__ float prm[512];

    const int t = threadIdx.x;
    if (t < 64) {
        float a0v = g0[t] / sqrtf(v0[t] + 1e-5f);
        prm[t]       = a0v;
        prm[64 + t]  = b0[t] - m0[t] * a0v;
        float a1v = g1[t] / sqrtf(v1[t] + 1e-5f);
        prm[128 + t] = a1v;
        prm[192 + t] = b1[t] - m1[t] * a1v;
    } else if (t < 192) {
        int o = t - 64;
        float a2v = g2[o] / sqrtf(v2[o] + 1e-5f);
        prm[256 + o] = a2v;
        prm[384 + o] = b2[o] - m2[o] * a2v;
    }
    for (int idx = t; idx < 64 * 68; idx += 256) {
        int o = idx / 68, i = idx - o * 68;
        float v;
        if (i < 64)      v = w0[o * 67 + 3 + i];
        else if (i < 67) v = w0[o * 67 + (i - 64)];
        else             v = 0.0f;
        regA[idx] = v;
    }
    for (int idx = t; idx < 64 * 64; idx += 256) regB[idx] = w1[idx];
    __syncthreads();

    const int gid = blockIdx.x * 256 + t;
    const int sl  = gid >> 5;
    const int s   = sl & (SCENT - 1);
    const int b   = sl >> 11;
    const int nidx = knn_idx[gid];

    const float* q  = new_xyz + (size_t)(b * SCENT + s) * 3;
    const float* P3 = xyz + (size_t)(b * NPTS + nidx) * 3;
    const float dx = P3[0] - q[0], dy = P3[1] - q[1], dz = P3[2] - q[2];

    const float4* F = (const float4*)(ptsT + ((size_t)b * NPTS + nidx) * 64);
    float4 xv[17];
#pragma unroll
    for (int i = 0; i < 16; ++i) xv[i] = F[i];
    xv[16] = make_float4(dx, dy, dz, 0.0f);

    float h0[64];
    const float4* W0 = (const float4*)regA;
#pragma unroll
    for (int o = 0; o < 64; ++o) {
        float acc = 0.f;
#pragma unroll
        for (int i = 0; i < 17; ++i) {
            float4 w = W0[o * 17 + i];
            acc = fmaf(xv[i].x, w.x, acc);
            acc = fmaf(xv[i].y, w.y, acc);
            acc = fmaf(xv[i].z, w.z, acc);
            acc = fmaf(xv[i].w, w.w, acc);
        }
        h0[o] = fmaxf(fmaf(acc, prm[o], prm[64 + o]), 0.f);
    }
    __syncthreads();
    for (int idx = t; idx < 128 * 64; idx += 256) regA[idx] = w2[idx];
    __syncthreads();

    float h1[64];
    const float4* W1 = (const float4*)regB;
#pragma unroll
    for (int o = 0; o < 64; ++o) {
        float acc = 0.f;
#pragma unroll
        for (int i = 0; i < 16; ++i) {
            float4 w = W1[o * 16 + i];
            acc = fmaf(h0[4 * i + 0], w.x, acc);
            acc = fmaf(h0[4 * i + 1], w.y, acc);
            acc = fmaf(h0[4 * i + 2], w.z, acc);
            acc = fmaf(h0[4 * i + 3], w.w, acc);
        }
        h1[o] = fmaxf(fmaf(acc, prm[128 + o], prm[192 + o]), 0.f);
    }

    const float4* W2 = (const float4*)regA;
    float* outp = out_points + (size_t)b * 128 * SCENT + s;
    const int lane = t & 63;
#pragma unroll 1
    for (int o = 0; o < 128; ++o) {
        float acc = 0.f;
#pragma unroll
        for (int i = 0; i < 16; ++i) {
            float4 w = W2[o * 16 + i];
            acc = fmaf(h1[4 * i + 0], w.x, acc);
            acc = fmaf(h1[4 * i + 1], w.y, acc);
            acc = fmaf(h1[4 * i + 2], w.z, acc);
            acc = fmaf(h1[4 * i + 3], w.w, acc);
        }
        float y = fmaxf(fmaf(acc, prm[256 + o], prm[384 + o]), 0.f);
#pragma unroll
        for (int off = 16; off >= 1; off >>= 1) y = fmaxf(y, __shfl_xor(y, off));
        if ((lane & 31) == 0) outp[(size_t)o * SCENT] = y;
    }
}

// ---------------------------------------------------------------------------
extern "C" void kernel_launch(void* const* d_in, const int* in_sizes, int n_in,
                              void* d_out, int out_size, void* d_ws, size_t ws_size,
                              hipStream_t stream) {
    const float* xyz    = (const float*)d_in[0];
    const float* points = (const float*)d_in[1];
    const float* w0 = (const float*)d_in[2];
    const float* g0 = (const float*)d_in[3];
    const float* b0 = (const float*)d_in[4];
    const float* m0 = (const float*)d_in[5];
    const float* v0 = (const float*)d_in[6];
    const float* w1 = (const float*)d_in[7];
    const float* g1 = (const float*)d_in[8];
    const float* b1 = (const float*)d_in[9];
    const float* m1 = (const float*)d_in[10];
    const float* v1 = (const float*)d_in[11];
    const float* w2 = (const float*)d_in[12];
    const float* g2 = (const float*)d_in[13];
    const float* b2 = (const float*)d_in[14];
    const float* m2 = (const float*)d_in[15];
    const float* v2 = (const float*)d_in[16];

    float* out_xyz    = (float*)d_out;                               // (B,S,3)
    float* out_points = (float*)d_out + (size_t)BATCH * SCENT * 3;   // (B,128,S)

    char* ws = (char*)d_ws;
    int*   progress = (int*)ws;                       // 4 ints (poison 0xAA < 0)
    int*   knn_idx  = (int*)(ws + 32768);
    float* ptsT     = (float*)(ws + 32768 + (size_t)BATCH * SCENT * KNEIGH * 4);

    void* kargs[] = { (void*)&xyz, (void*)&out_xyz, (void*)&points,
                      (void*)&ptsT, (void*)&knn_idx, (void*)&progress };
    hipLaunchCooperativeKernel((const void*)fused_kernel,
                               dim3(BATCH + NCONS), dim3(FPS_T), kargs, 0, stream);

    mlp_kernel<<<(BATCH * SCENT * KNEIGH) / 256, 256, 0, stream>>>(
        xyz, out_xyz, ptsT, knn_idx,
        w0, g0, b0, m0, v0, w1, g1, b1, m1, v1, w2, g2, b2, m2, v2, out_points);
}

// Round 13
// 2485.540 us; speedup vs baseline: 1.1110x; 1.0446x over previous
//
#include <hip/hip_runtime.h>
#include <cfloat>
#include <climits>

#define NPTS   8192
#define SCENT  2048
#define KNEIGH 32
#define BATCH  4
#define DFEAT  64
#define FPS_T  512
#define NV     8       // v2f pairs per thread (16 points)
#define NW     8       // waves per block
#define CAP    64      // fallback candidate capacity
#define NCONS  252     // consumer blocks
#define CPB    63      // consumer blocks per batch

typedef float v2f __attribute__((ext_vector_type(2)));

// DPP max step over uint (positive-f32 bit pattern preserves order).
#define DPPMAX(u, ctrl, rmask)                                                        \
    { unsigned _t = (unsigned)__builtin_amdgcn_update_dpp(0, (int)(u), (ctrl),        \
                                                          (rmask), 0xf, false);      \
      (u) = ((u) > _t) ? (u) : _t; }

struct FpsSh {                       // ~123.5 KB
    float sx[NPTS], sy[NPTS], sz[NPTS];
    float hx[SCENT], hy[SCENT], hz[SCENT];
    alignas(16) unsigned slotV[2][NW];
    alignas(16) unsigned slotM[2][NW];
    int scand[CAP];
    int scnt;
    alignas(8) double sdd[2][NW];
    double sfv[NW];
    int sfo[NW];
};
struct ConsSh {                      // ~111 KB: KNN buffers + MLP weights
    float  spx[2048], spy[2048], spz[2048];
    double sp2[2048];
    float  tile[32 * 33];
    float  regA[64 * 68];            // w0 permuted/padded
    float  regB[64 * 64];            // w1
    float  regC[128 * 64];           // w2
    float  prm[512];
};
union ShU { FpsSh f; ConsSh c; };

// ---------------------------------------------------------------------------
// Fully fused cooperative kernel.
// Blocks 0..3: FPS producer (R11 chain; f32 fast path + exact-f64 fallback,
// proof as R3..R11), flushing 64-centroid chunks + release-publishing
// progress[b].
// Blocks 4..255: transpose slice -> weights into LDS -> per-round: acquire
// progress, wave-per-query f64-exact KNN (indices stay in lanes 0..31), then
// IMMEDIATE per-wave MLP (thread-per-neighbor, LDS-broadcast weights) + max
// over K, writing out_points. MLP hides under the FPS critical path.
// ---------------------------------------------------------------------------
__global__ __launch_bounds__(FPS_T, 1) void fused_kernel(
        const float* __restrict__ xyz, float* __restrict__ new_xyz,
        const float* __restrict__ pts, float* __restrict__ ptsT,
        int* __restrict__ progress, int* __restrict__ tcount,
        float* __restrict__ out_points,
        const float* __restrict__ w0, const float* __restrict__ g0,
        const float* __restrict__ b0, const float* __restrict__ m0,
        const float* __restrict__ v0, const float* __restrict__ w1,
        const float* __restrict__ g1, const float* __restrict__ b1,
        const float* __restrict__ m1, const float* __restrict__ v1,
        const float* __restrict__ w2, const float* __restrict__ g2,
        const float* __restrict__ b2, const float* __restrict__ m2,
        const float* __restrict__ v2) {
    __shared__ ShU sh;
    const int t = threadIdx.x;
    const int lane = t & 63, w = t >> 6;

    if (blockIdx.x < BATCH) {
        // ==================== FPS producer ====================
        FpsSh& S = sh.f;
        const int b = blockIdx.x;
        const float* X = xyz + (size_t)b * NPTS * 3;

        for (int p = t; p < NPTS; p += FPS_T) {
            S.sx[p] = X[3 * p + 0]; S.sy[p] = X[3 * p + 1]; S.sz[p] = X[3 * p + 2];
        }

        v2f px2[NV], py2[NV], pz2[NV], dist2[NV];
#pragma unroll
        for (int j = 0; j < NV; ++j) {
            int pA = t + FPS_T * j, pB = t + FPS_T * (j + NV);
            px2[j] = (v2f){X[3 * pA + 0], X[3 * pB + 0]};
            py2[j] = (v2f){X[3 * pA + 1], X[3 * pB + 1]};
            pz2[j] = (v2f){X[3 * pA + 2], X[3 * pB + 2]};
            dist2[j] = (v2f){1e10f, 1e10f};
        }
        float cx = X[0], cy = X[1], cz = X[2];
        int buf = 0;
        __syncthreads();

#pragma unroll 1
        for (int s = 0; s < SCENT; ++s) {
            if (t == 0) { S.hx[s] = cx; S.hy[s] = cy; S.hz[s] = cz; }

            const v2f cxx = {cx, cx}, cyy = {cy, cy}, czz = {cz, cz};
            v2f m2 = {-1.f, -1.f}, s2 = {-1.f, -1.f};
#pragma unroll
            for (int j = 0; j < NV; ++j) {
                v2f dx = px2[j] - cxx;
                v2f dy = py2[j] - cyy;
                v2f dz = pz2[j] - czz;
                v2f d  = __builtin_elementwise_fma(dx, dx,
                         __builtin_elementwise_fma(dy, dy, dz * dz));
                v2f nd = __builtin_elementwise_min(dist2[j], d);
                dist2[j] = nd;
                v2f lo = __builtin_elementwise_min(m2, nd);
                s2 = __builtin_elementwise_max(s2, lo);
                m2 = __builtin_elementwise_max(m2, nd);
            }
            const float m   = fmaxf(m2.x, m2.y);
            const float sec = fmaxf(fmaxf(s2.x, s2.y), fminf(m2.x, m2.y));

            int mi = 0;
#pragma unroll
            for (int j = 0; j < NV; ++j) {
                mi = (dist2[j].x == m) ? (t + FPS_T * j)        : mi;
                mi = (dist2[j].y == m) ? (t + FPS_T * (j + NV)) : mi;
            }

            unsigned myU = __float_as_uint(m);
            unsigned u = myU;
            DPPMAX(u, 0x111, 0xf);
            DPPMAX(u, 0x112, 0xf);
            DPPMAX(u, 0x114, 0xf);
            DPPMAX(u, 0x118, 0xf);
            DPPMAX(u, 0x142, 0xa);
            DPPMAX(u, 0x143, 0xc);
            const unsigned wu = (unsigned)__builtin_amdgcn_readlane((int)u, 63);

            unsigned long long wb = __ballot(myU == wu);
            const int wl   = __ffsll(wb) - 1;
            const int widx = __builtin_amdgcn_readlane(mi, wl);
            const float thwf = __fmul_rn(__uint_as_float(wu), 0.999998f);
            unsigned long long b1m = __ballot(m >= thwf);
            unsigned long long b2m = __ballot(sec >= thwf);
            const unsigned tw = (b2m || __popcll(b1m) >= 2) ? 1u : 0u;
            if (lane == 0) {
                S.slotV[buf][w] = wu;
                S.slotM[buf][w] = (unsigned)widx | (tw << 14);
            }
            __syncthreads();                                  // the ONE barrier

            unsigned sv[NW], sm[NW];
            {
                const uint4* vp = (const uint4*)&S.slotV[buf][0];
                const uint4* mp = (const uint4*)&S.slotM[buf][0];
                uint4 a = vp[0], c = vp[1], e = mp[0], f = mp[1];
                sv[0] = a.x; sv[1] = a.y; sv[2] = a.z; sv[3] = a.w;
                sv[4] = c.x; sv[5] = c.y; sv[6] = c.z; sv[7] = c.w;
                sm[0] = e.x; sm[1] = e.y; sm[2] = e.z; sm[3] = e.w;
                sm[4] = f.x; sm[5] = f.y; sm[6] = f.z; sm[7] = f.w;
            }
            unsigned gu = sv[0];
#pragma unroll
            for (int k = 1; k < NW; ++k) gu = (sv[k] > gu) ? sv[k] : gu;
            const float gvf  = __uint_as_float(gu);
            const float gthf = __fmul_rn(gvf, 0.999998f);
            const unsigned ugth = __float_as_uint(gthf);
            int nw = 0; unsigned meta = 0;
#pragma unroll
            for (int k = NW - 1; k >= 0; --k) {
                nw += (sv[k] >= ugth) ? 1 : 0;
                meta = (sv[k] == gu) ? sm[k] : meta;
            }
            const int wtie = (meta >> 14) & 1;
            int i1 = (int)(meta & 0x3fffu);

            if (nw >= 2 || wtie) {
                // ---- exact f64 fallback (block-uniform, rare) ----
                if (t == 0) S.scnt = 0;
                __syncthreads();
#pragma unroll
                for (int j = 0; j < NV; ++j) {
                    if (dist2[j].x >= gthf) {
                        int slot = atomicAdd(&S.scnt, 1);
                        if (slot < CAP) S.scand[slot] = t + FPS_T * j;
                    }
                    if (dist2[j].y >= gthf) {
                        int slot = atomicAdd(&S.scnt, 1);
                        if (slot < CAP) S.scand[slot] = t + FPS_T * (j + NV);
                    }
                }
                __syncthreads();
                const int mm = S.scnt;
                if (mm <= CAP) {
                    double bd = -1.0; int bi = INT_MAX;
#pragma unroll 1
                    for (int k = 0; k < mm; ++k) {
                        const int pos = S.scand[k];
                        const double pxd = (double)S.sx[pos], pyd = (double)S.sy[pos],
                                     pzd = (double)S.sz[pos];
                        double dd = 1e10;
                        for (int i = t; i <= s; i += FPS_T) {
                            double ddx = __dsub_rn(pxd, (double)S.hx[i]);
                            double ddy = __dsub_rn(pyd, (double)S.hy[i]);
                            double ddz = __dsub_rn(pzd, (double)S.hz[i]);
                            double d = __dadd_rn(__dadd_rn(__dmul_rn(ddx, ddx), __dmul_rn(ddy, ddy)),
                                                 __dmul_rn(ddz, ddz));
                            dd = fmin(dd, d);
                        }
#pragma unroll
                        for (int off = 32; off >= 1; off >>= 1)
                            dd = fmin(dd, __shfl_down(dd, off));
                        if (lane == 0) S.sdd[k & 1][w] = dd;
                        __syncthreads();
                        double ddm = S.sdd[k & 1][0];
#pragma unroll
                        for (int w2i = 1; w2i < NW; ++w2i) ddm = fmin(ddm, S.sdd[k & 1][w2i]);
                        if (ddm > bd || (ddm == bd && pos < bi)) { bd = ddm; bi = pos; }
                    }
                    i1 = bi;
                } else {
                    // safety net: full exact scan (practically unreachable)
                    double bv = -1.0; int bi = INT_MAX;
#pragma unroll 1
                    for (int j = 0; j < 2 * NV; ++j) {
                        const int jj = j & (NV - 1);
                        const bool hiHalf = j >= NV;
                        const double pxd = (double)(hiHalf ? px2[jj].y : px2[jj].x);
                        const double pyd = (double)(hiHalf ? py2[jj].y : py2[jj].x);
                        const double pzd = (double)(hiHalf ? pz2[jj].y : pz2[jj].x);
                        double dd = 1e10;
                        for (int i = 0; i <= s; ++i) {
                            double ddx = __dsub_rn(pxd, (double)S.hx[i]);
                            double ddy = __dsub_rn(pyd, (double)S.hy[i]);
                            double ddz = __dsub_rn(pzd, (double)S.hz[i]);
                            double d = __dadd_rn(__dadd_rn(__dmul_rn(ddx, ddx), __dmul_rn(ddy, ddy)),
                                                 __dmul_rn(ddz, ddz));
                            dd = fmin(dd, d);
                        }
                        int pidx = t + FPS_T * j;
                        if (dd > bv || (dd == bv && pidx < bi)) { bv = dd; bi = pidx; }
                    }
#pragma unroll
                    for (int off = 32; off >= 1; off >>= 1) {
                        double ov = __shfl_down(bv, off);
                        int    oi = __shfl_down(bi, off);
                        if (ov > bv || (ov == bv && oi < bi)) { bv = ov; bi = oi; }
                    }
                    if (lane == 0) { S.sfv[w] = bv; S.sfo[w] = bi; }
                    __syncthreads();
                    bv = S.sfv[0]; bi = S.sfo[0];
#pragma unroll
                    for (int w2i = 1; w2i < NW; ++w2i) {
                        double ov = S.sfv[w2i]; int oi = S.sfo[w2i];
                        if (ov > bv || (ov == bv && oi < bi)) { bv = ov; bi = oi; }
                    }
                    i1 = bi;
                }
                __syncthreads();
            }
            cx = S.sx[i1]; cy = S.sy[i1]; cz = S.sz[i1];

            // ---- chunked flush + release publish every 64 centroids ----
            if ((s & 63) == 63) {
                const int base0 = s - 63;
                if (t < 64 * 3) {
                    int ci = base0 + t / 3;
                    int cmp = t - (t / 3) * 3;
                    float v = (cmp == 0) ? S.hx[ci] : ((cmp == 1) ? S.hy[ci] : S.hz[ci]);
                    __hip_atomic_store(&new_xyz[((size_t)b * SCENT + base0) * 3 + t], v,
                                       __ATOMIC_RELAXED, __HIP_MEMORY_SCOPE_AGENT);
                }
                __syncthreads();   // vmcnt(0) drain => stores device-visible
                if (t == 0)
                    __hip_atomic_store(&progress[b], s + 1,
                                       __ATOMIC_RELEASE, __HIP_MEMORY_SCOPE_AGENT);
            }
            buf ^= 1;
        }
    } else {
        // ============ consumers: transpose + weights + gated KNN + MLP ============
        ConsSh& K = sh.c;
        const int local = blockIdx.x - BATCH;     // 0..251
        const int batch = local / CPB;            // 0..3
        const int cl    = local % CPB;            // 0..62
        const int tx = t & 31, ty = t >> 5;       // ty 0..15

        // ---- transpose slice: (B,D,N) -> (B,N,D), 32x32 tiles ----
        for (int tid2 = local; tid2 < 2048; tid2 += NCONS) {
            const int bt = tid2 >> 9, rest = tid2 & 511;
            const int d0 = (rest >> 8) * 32, n0 = (rest & 255) * 32;
            __syncthreads();
#pragma unroll
            for (int i = 0; i < 2; ++i)
                K.tile[(ty + 16 * i) * 33 + tx] =
                    pts[(size_t)bt * DFEAT * NPTS + (size_t)(d0 + ty + 16 * i) * NPTS + n0 + tx];
            __syncthreads();
#pragma unroll
            for (int i = 0; i < 2; ++i)
                ptsT[(size_t)bt * NPTS * DFEAT + (size_t)(n0 + ty + 16 * i) * DFEAT + d0 + tx] =
                    K.tile[tx * 33 + ty + 16 * i];
        }
        if (t == 0) {
            __threadfence();                          // drain ptsT stores
            atomicAdd(tcount, 1);                     // device-scope arrival
        }

        // ---- stage folded weights in LDS ----
        for (int idx = t; idx < 64 * 68; idx += FPS_T) {
            int o = idx / 68, i = idx - o * 68;
            float v;
            if (i < 64)      v = w0[o * 67 + 3 + i];
            else if (i < 67) v = w0[o * 67 + (i - 64)];
            else             v = 0.0f;
            K.regA[idx] = v;
        }
        for (int idx = t; idx < 64 * 64; idx += FPS_T)  K.regB[idx] = w1[idx];
        for (int idx = t; idx < 128 * 64; idx += FPS_T) K.regC[idx] = w2[idx];
        if (t < 64) {
            float a0v = g0[t] / sqrtf(v0[t] + 1e-5f);
            K.prm[t]       = a0v;
            K.prm[64 + t]  = b0[t] - m0[t] * a0v;
            float a1v = g1[t] / sqrtf(v1[t] + 1e-5f);
            K.prm[128 + t] = a1v;
            K.prm[192 + t] = b1[t] - m1[t] * a1v;
        } else if (t < 192) {
            int o = t - 64;
            float a2v = g2[o] / sqrtf(v2[o] + 1e-5f);
            K.prm[256 + o] = a2v;
            K.prm[384 + o] = b2[o] - m2[o] * a2v;
        }
        // (visibility of weights across waves covered by in-round barriers)

        const float* Xb = xyz + (size_t)batch * NPTS * 3;
#pragma unroll 1
        for (int r = 0; ; ++r) {
            const int sBase = r * (CPB * NW) + cl * NW;
            if (sBase >= SCENT) break;
            const int sMax = min(sBase + NW - 1, SCENT - 1);
            if (t == 0) {
                while (__hip_atomic_load(&progress[batch], __ATOMIC_ACQUIRE,
                                         __HIP_MEMORY_SCOPE_AGENT) < sMax + 1)
                    __builtin_amdgcn_s_sleep(8);
                if (r == 0) {                         // ptsT complete before any MLP gather
                    while (__hip_atomic_load(tcount, __ATOMIC_ACQUIRE,
                                             __HIP_MEMORY_SCOPE_AGENT) < NCONS)
                        __builtin_amdgcn_s_sleep(8);
                }
            }
            __syncthreads();

            const int sQ = min(sBase + w, SCENT - 1);
            const float* q = new_xyz + ((size_t)batch * SCENT + sQ) * 3;
            const float qfx = q[0], qfy = q[1], qfz = q[2];
            const double qx = (double)qfx, qy = (double)qfy, qz = (double)qfz;
            const double q2 = __dadd_rn(__dadd_rn(__dmul_rn(qx, qx), __dmul_rn(qy, qy)),
                                        __dmul_rn(qz, qz));

            double ld   = DBL_MAX;
            int    li   = 0x7fffffff;
            double taud = DBL_MAX;
            int    taui = 0x7fffffff;

#pragma unroll 1
            for (int c = 0; c < 4; ++c) {
                __syncthreads();
#pragma unroll
                for (int r2 = 0; r2 < 4; ++r2) {
                    int pl = r2 * 512 + t;
                    int p  = c * 2048 + pl;
                    float x = Xb[3 * p + 0], y = Xb[3 * p + 1], z = Xb[3 * p + 2];
                    K.spx[pl] = x; K.spy[pl] = y; K.spz[pl] = z;
                    double dx = (double)x, dy = (double)y, dz = (double)z;
                    K.sp2[pl] = __dadd_rn(__dadd_rn(__dmul_rn(dx, dx), __dmul_rn(dy, dy)),
                                          __dmul_rn(dz, dz));
                }
                __syncthreads();
#pragma unroll 1
                for (int i = 0; i < 32; ++i) {
                    const int pl   = i * 64 + lane;
                    const int pidx = c * 2048 + pl;
                    double px = (double)K.spx[pl], py = (double)K.spy[pl],
                           pz = (double)K.spz[pl];
                    double qp = __dadd_rn(__dadd_rn(__dmul_rn(qx, px), __dmul_rn(qy, py)),
                                          __dmul_rn(qz, pz));
                    double d  = __dsub_rn(__dadd_rn(q2, K.sp2[pl]), __dmul_rn(2.0, qp));
                    bool cand = (d < taud) || (d == taud && pidx < taui);
                    unsigned long long mmask = __ballot(cand);
                    while (mmask) {
                        int sl = __ffsll((unsigned long long)mmask) - 1;
                        mmask &= mmask - 1;
                        double dv = __shfl(d, sl);
                        int    iv = __shfl(pidx, sl);
                        if (dv < taud || (dv == taud && iv < taui)) {
                            bool gt = (lane < 32) && (ld > dv || (ld == dv && li > iv));
                            unsigned long long gm = __ballot(gt);
                            double ud = __shfl_up(ld, 1);
                            int    ui = __shfl_up(li, 1);
                            if (gt) { ld = ud; li = ui; }
                            bool first = gt && ((lane == 0) || !((gm >> (lane - 1)) & 1ull));
                            if (first) { ld = dv; li = iv; }
                            taud = __shfl(ld, 31);
                            taui = __shfl(li, 31);
                        }
                    }
                }
            }

            // ---- immediate per-wave MLP (thread-per-neighbor, lanes 0..31) ----
            if (sBase + w < SCENT && lane < 32) {
                const int nidx = li;
                const float* P3 = Xb + (size_t)nidx * 3;
                const float dx = P3[0] - qfx, dy = P3[1] - qfy, dz = P3[2] - qfz;

                const float4* F = (const float4*)(ptsT + ((size_t)batch * NPTS + nidx) * 64);
                float4 xv[17];
#pragma unroll
                for (int i = 0; i < 16; ++i) xv[i] = F[i];
                xv[16] = make_float4(dx, dy, dz, 0.0f);

                float h0[64];
                const float4* W0 = (const float4*)K.regA;
#pragma unroll
                for (int o = 0; o < 64; ++o) {
                    float acc = 0.f;
#pragma unroll
                    for (int i = 0; i < 17; ++i) {
                        float4 ww = W0[o * 17 + i];
                        acc = fmaf(xv[i].x, ww.x, acc);
                        acc = fmaf(xv[i].y, ww.y, acc);
                        acc = fmaf(xv[i].z, ww.z, acc);
                        acc = fmaf(xv[i].w, ww.w, acc);
                    }
                    h0[o] = fmaxf(fmaf(acc, K.prm[o], K.prm[64 + o]), 0.f);
                }
                float h1[64];
                const float4* W1 = (const float4*)K.regB;
#pragma unroll
                for (int o = 0; o < 64; ++o) {
                    float acc = 0.f;
#pragma unroll
                    for (int i = 0; i < 16; ++i) {
                        float4 ww = W1[o * 16 + i];
                        acc = fmaf(h0[4 * i + 0], ww.x, acc);
                        acc = fmaf(h0[4 * i + 1], ww.y, acc);
                        acc = fmaf(h0[4 * i + 2], ww.z, acc);
                        acc = fmaf(h0[4 * i + 3], ww.w, acc);
                    }
                    h1[o] = fmaxf(fmaf(acc, K.prm[128 + o], K.prm[192 + o]), 0.f);
                }
                const float4* W2 = (const float4*)K.regC;
                float* outp = out_points + (size_t)batch * 128 * SCENT + sQ;
#pragma unroll 1
                for (int o = 0; o < 128; ++o) {
                    float acc = 0.f;
#pragma unroll
                    for (int i = 0; i < 16; ++i) {
                        float4 ww = W2[o * 16 + i];
                        acc = fmaf(h1[4 * i + 0], ww.x, acc);
                        acc = fmaf(h1[4 * i + 1], ww.y, acc);
                        acc = fmaf(h1[4 * i + 2], ww.z, acc);
                        acc = fmaf(h1[4 * i + 3], ww.w, acc);
                    }
                    float y = fmaxf(fmaf(acc, K.prm[256 + o], K.prm[384 + o]), 0.f);
#pragma unroll
                    for (int off = 16; off >= 1; off >>= 1)
                        y = fmaxf(y, __shfl_xor(y, off));
                    if (lane == 0) outp[(size_t)o * SCENT] = y;
                }
            }
        }
    }
}

// ---------------------------------------------------------------------------
extern "C" void kernel_launch(void* const* d_in, const int* in_sizes, int n_in,
                              void* d_out, int out_size, void* d_ws, size_t ws_size,
                              hipStream_t stream) {
    const float* xyz    = (const float*)d_in[0];
    const float* points = (const float*)d_in[1];
    const float* w0 = (const float*)d_in[2];
    const float* g0 = (const float*)d_in[3];
    const float* b0 = (const float*)d_in[4];
    const float* m0 = (const float*)d_in[5];
    const float* v0 = (const float*)d_in[6];
    const float* w1 = (const float*)d_in[7];
    const float* g1 = (const float*)d_in[8];
    const float* b1 = (const float*)d_in[9];
    const float* m1 = (const float*)d_in[10];
    const float* v1 = (const float*)d_in[11];
    const float* w2 = (const float*)d_in[12];
    const float* g2 = (const float*)d_in[13];
    const float* b2 = (const float*)d_in[14];
    const float* m2 = (const float*)d_in[15];
    const float* v2 = (const float*)d_in[16];

    float* out_xyz    = (float*)d_out;                               // (B,S,3)
    float* out_points = (float*)d_out + (size_t)BATCH * SCENT * 3;   // (B,128,S)

    char* ws = (char*)d_ws;
    int*   progress = (int*)ws;                       // 4 ints @ ws+0
    int*   tcount   = (int*)(ws + 64);                // 1 int  @ ws+64
    float* ptsT     = (float*)(ws + 32768);

    hipMemsetAsync(ws, 0, 128, stream);               // zero progress + tcount

    void* kargs[] = { (void*)&xyz, (void*)&out_xyz, (void*)&points, (void*)&ptsT,
                      (void*)&progress, (void*)&tcount, (void*)&out_points,
                      (void*)&w0, (void*)&g0, (void*)&b0, (void*)&m0, (void*)&v0,
                      (void*)&w1, (void*)&g1, (void*)&b1, (void*)&m1, (void*)&v1,
                      (void*)&w2, (void*)&g2, (void*)&b2, (void*)&m2, (void*)&v2 };
    hipLaunchCooperativeKernel((const void*)fused_kernel,
                               dim3(BATCH + NCONS), dim3(FPS_T), kargs, 0, stream);
}